// Round 9
// baseline (651.690 us; speedup 1.0000x reference)
//
#include <hip/hip_runtime.h>
#include <math.h>

// ---------------- problem constants ----------------
#define B_SZ    16
#define N_ROWS  8192
#define D       768
#define EPS_LN  1e-6f
#define EPS_POOL 1e-6f
#define SCALE   0.03608439182435161f   // 768^-0.5

#define ROWS_PER_BLOCK 64
#define ROWS_PER_WAVE  16
#define BLOCKS_PER_B   (N_ROWS / ROWS_PER_BLOCK)   // 128
#define NBLK_PASS      (B_SZ * BLOCKS_PER_B)       // 2048

// ---------------- workspace layout (float offsets) ----------------
#define WS_COLSUM   0                       // B*D = 12288 (zeroed by k0)
#define WS_R        (WS_COLSUM + B_SZ*D)    // B*D = 12288 (zeroed by k0)
#define WS_QQ       (WS_R + B_SZ*D)         // B*D
#define WS_GMIN     (WS_QQ + B_SZ*D)        // 1 uint (init +inf), pad 32
#define WS_STAT     (WS_GMIN + 32)          // B*N*2 floats: (rstd, rmu) per row
#define WS_PART     (WS_STAT + 2*B_SZ*N_ROWS)  // NBLK_PASS * PART_STRIDE
#define PART_STRIDE 1544                    // [0]=m [1]=se [8..775]=a1 [776..1543]=a2
// total ≈ 3.46 M floats ≈ 13.9 MB

// ---------------- helpers ----------------
__device__ __forceinline__ void atomicMinFloat(unsigned int* addr, float val) {
    if (val >= 0.0f) atomicMin((int*)addr, __float_as_int(val));
    else             atomicMax(addr, __float_as_uint(val));
}
__device__ __forceinline__ float hsum4(float4 v)  { return (v.x + v.y) + (v.z + v.w); }
__device__ __forceinline__ float hsumsq4(float4 v){ return (v.x*v.x + v.y*v.y) + (v.z*v.z + v.w*v.w); }

// ---------------- K0: init colsum, r, gmin ----------------
__global__ __launch_bounds__(256) void k0_init(float* __restrict__ ws) {
    int i = blockIdx.x * 256 + threadIdx.x;
    if (i < 2 * B_SZ * D) ws[i] = 0.0f;          // colsum + r (contiguous)
    if (i == 0) ((unsigned int*)ws)[WS_GMIN] = 0x7F800000u;  // +inf
}

// ---------------- KA: pass 1 — colsum + LN stats + global kv-min ----------------
__global__ __launch_bounds__(256) void ka_stats(const float* __restrict__ x,
                                                const float* __restrict__ lnw,
                                                const float* __restrict__ lnb,
                                                float* __restrict__ ws) {
    __shared__ float lds[4][D];
    __shared__ float wvmin[4];
    const int tid  = threadIdx.x;
    const int lane = tid & 63;
    const int wv   = tid >> 6;
    const int b    = blockIdx.x >> 7;          // /128
    const int chunk= blockIdx.x & 127;
    const int n0   = chunk * ROWS_PER_BLOCK + wv * ROWS_PER_WAVE;
    const float* base = x + ((size_t)b * N_ROWS + n0) * D + 4*lane;

    float w[12], cb[12];
    #pragma unroll
    for (int g = 0; g < 3; ++g) {
        const float4 vw = *(const float4*)(lnw + 4*lane + 256*g);
        const float4 vc = *(const float4*)(lnb + 4*lane + 256*g);
        w[4*g]=vw.x; w[4*g+1]=vw.y; w[4*g+2]=vw.z; w[4*g+3]=vw.w;
        cb[4*g]=vc.x; cb[4*g+1]=vc.y; cb[4*g+2]=vc.z; cb[4*g+3]=vc.w;
    }

    float cs[12];
    #pragma unroll
    for (int k = 0; k < 12; ++k) cs[k] = 0.0f;
    float kvmin = INFINITY;

    float2* stat = (float2*)(ws + WS_STAT) + (size_t)b * N_ROWS;

    for (int i = 0; i < ROWS_PER_WAVE; ++i) {
        const int n = n0 + i;
        const float* row = base + (size_t)i * D;
        float xv[12];
        float s = 0.0f, ss = 0.0f;
        #pragma unroll
        for (int g = 0; g < 3; ++g) {
            const float4 v = *(const float4*)(row + 256*g);
            xv[4*g]=v.x; xv[4*g+1]=v.y; xv[4*g+2]=v.z; xv[4*g+3]=v.w;
            s  += hsum4(v);
            ss += hsumsq4(v);
        }
        #pragma unroll
        for (int off = 32; off; off >>= 1) {
            s  += __shfl_xor(s,  off);
            ss += __shfl_xor(ss, off);
        }
        const float mu   = s * (1.0f / D);
        const float var  = ss * (1.0f / D) - mu * mu;
        const float rstd = rsqrtf(var + EPS_LN);
        const float rmu  = rstd * mu;
        if (lane == 0) stat[n] = make_float2(rstd, rmu);

        #pragma unroll
        for (int k = 0; k < 12; ++k) {
            cs[k] += xv[k];
            const float z  = rstd * xv[k] - rmu;
            const float kv = z * w[k] + cb[k];
            kvmin = fminf(kvmin, kv);
        }
    }

    #pragma unroll
    for (int off = 32; off; off >>= 1) kvmin = fminf(kvmin, __shfl_xor(kvmin, off));
    if (lane == 0) wvmin[wv] = kvmin;

    #pragma unroll
    for (int g = 0; g < 3; ++g)
        *(float4*)&lds[wv][4*lane + 256*g] =
            make_float4(cs[4*g], cs[4*g+1], cs[4*g+2], cs[4*g+3]);
    __syncthreads();

    float* colsum = ws + WS_COLSUM + (size_t)b * D;
    #pragma unroll
    for (int k = 0; k < 3; ++k) {
        const int c = tid + 256*k;
        atomicAdd(&colsum[c], lds[0][c] + lds[1][c] + lds[2][c] + lds[3][c]);
    }
    if (tid == 0) {
        float m = fminf(fminf(wvmin[0], wvmin[1]), fminf(wvmin[2], wvmin[3]));
        atomicMinFloat((unsigned int*)ws + WS_GMIN, m);
    }
}

// ---------------- KB1: qq[b,i] = SCALE * dot(wq[i,:], q[b]) ----------------
// grid = 16 b * 12 i-chunks(64)
__global__ __launch_bounds__(256) void kb1_qq(const float* __restrict__ wq,
                                              float* __restrict__ ws) {
    __shared__ float q[D];
    const int tid  = threadIdx.x;
    const int lane = tid & 63;
    const int wv   = tid >> 6;
    const int b    = blockIdx.x / 12;
    const int ic   = blockIdx.x % 12;

    const float* colsum = ws + WS_COLSUM + (size_t)b * D;
    for (int c = tid; c < D; c += 256) q[c] = colsum[c] * (1.0f / N_ROWS);
    __syncthreads();

    for (int k = 0; k < 16; ++k) {
        const int i = ic * 64 + wv * 16 + k;
        const float* row = wq + (size_t)i * D + 4*lane;
        float p = 0.0f;
        #pragma unroll
        for (int g = 0; g < 3; ++g) {
            const float4 a = *(const float4*)(row + 256*g);
            const int c = 4*lane + 256*g;
            p += a.x*q[c] + a.y*q[c+1] + a.z*q[c+2] + a.w*q[c+3];
        }
        #pragma unroll
        for (int off = 32; off; off >>= 1) p += __shfl_xor(p, off);
        if (lane == 0) ws[WS_QQ + (size_t)b * D + i] = p * SCALE;
    }
}

// ---------------- KB2: r[b,j] += sum_i qq[b,i]*wk[i,j] ----------------
// grid = 3 j-tiles(256) * 16 i-chunks(48)
__global__ __launch_bounds__(256) void kb2_r(const float* __restrict__ wk,
                                             float* __restrict__ ws) {
    __shared__ float qs[16][48];
    const int tid = threadIdx.x;
    const int jt  = blockIdx.x / 16;
    const int ic  = blockIdx.x % 16;

    #pragma unroll
    for (int k = 0; k < 3; ++k) {
        const int v  = tid + 256*k;       // 0..767
        const int bb = v / 48, ii = v % 48;
        qs[bb][ii] = ws[WS_QQ + (size_t)bb * D + ic*48 + ii];
    }
    __syncthreads();

    float acc[16];
    #pragma unroll
    for (int bb = 0; bb < 16; ++bb) acc[bb] = 0.0f;

    const int j = jt * 256 + tid;
    for (int i = 0; i < 48; ++i) {
        const float wkv = wk[(size_t)(ic*48 + i) * D + j];
        #pragma unroll
        for (int bb = 0; bb < 16; ++bb) acc[bb] += qs[bb][i] * wkv;
    }
    #pragma unroll
    for (int bb = 0; bb < 16; ++bb)
        atomicAdd(&ws[WS_R + (size_t)bb * D + j], acc[bb]);
}

// ---------------- KC: pass 2 — logits + online softmax + moment accumulate ----------------
__global__ __launch_bounds__(256) void kc_fused(const float* __restrict__ x,
                                                const float* __restrict__ lnw,
                                                const float* __restrict__ lnb,
                                                float* __restrict__ ws) {
    __shared__ float lds_acc[4][2*D];   // 24 KB
    __shared__ float lds_ms[4], lds_se[4];
    const int tid  = threadIdx.x;
    const int lane = tid & 63;
    const int wv   = tid >> 6;
    // reversed block order: pass 1 left the tail of x in L3
    const int rb   = (NBLK_PASS - 1) - blockIdx.x;
    const int b    = rb >> 7;
    const int chunk= rb & 127;
    const int n0   = chunk * ROWS_PER_BLOCK + wv * ROWS_PER_WAVE;

    // per-lane slices of lnw, lnb, rw = r*lnw;  A = Σ rw, C = Σ r·lnb
    float w[12], cb[12], rw[12];
    float A = 0.0f, C = 0.0f;
    {
        const float* rbase = ws + WS_R + (size_t)b * D + 4*lane;
        #pragma unroll
        for (int g = 0; g < 3; ++g) {
            const float4 vw = *(const float4*)(lnw + 4*lane + 256*g);
            const float4 vc = *(const float4*)(lnb + 4*lane + 256*g);
            const float4 vr = *(const float4*)(rbase + 256*g);
            w[4*g]=vw.x; w[4*g+1]=vw.y; w[4*g+2]=vw.z; w[4*g+3]=vw.w;
            cb[4*g]=vc.x; cb[4*g+1]=vc.y; cb[4*g+2]=vc.z; cb[4*g+3]=vc.w;
            rw[4*g]  =vr.x*vw.x; rw[4*g+1]=vr.y*vw.y;
            rw[4*g+2]=vr.z*vw.z; rw[4*g+3]=vr.w*vw.w;
            C += vr.x*vc.x + vr.y*vc.y + vr.z*vc.z + vr.w*vc.w;
        }
        #pragma unroll
        for (int k = 0; k < 12; ++k) A += rw[k];
        #pragma unroll
        for (int off = 32; off; off >>= 1) {
            A += __shfl_xor(A, off); C += __shfl_xor(C, off);
        }
    }

    float m = -INFINITY, se = 0.0f;
    float T1[12], T2[12];
    #pragma unroll
    for (int k = 0; k < 12; ++k) { T1[k] = 0.0f; T2[k] = 0.0f; }

    const float* base = x + ((size_t)b * N_ROWS + n0) * D + 4*lane;
    const float2* stat = (const float2*)(ws + WS_STAT) + (size_t)b * N_ROWS;

    for (int i = 0; i < ROWS_PER_WAVE; ++i) {
        const int n = n0 + i;
        const float2 st = stat[n];          // (rstd, rmu) — wave-uniform broadcast
        float xv[12];
        float dt = 0.0f;
        {
            const float* row = base + (size_t)i * D;
            #pragma unroll
            for (int g = 0; g < 3; ++g) {
                const float4 v = *(const float4*)(row + 256*g);
                xv[4*g]=v.x; xv[4*g+1]=v.y; xv[4*g+2]=v.z; xv[4*g+3]=v.w;
                dt += rw[4*g]*v.x + rw[4*g+1]*v.y + rw[4*g+2]*v.z + rw[4*g+3]*v.w;
            }
        }
        #pragma unroll
        for (int off = 32; off; off >>= 1) dt += __shfl_xor(dt, off);

        const float logit = fmaf(st.x, dt, fmaf(-st.y, A, C));

        // online softmax (wave-uniform branch)
        if (logit > m) {
            const float f = __expf(m - logit);
            se *= f;
            #pragma unroll
            for (int k = 0; k < 12; ++k) { T1[k] *= f; T2[k] *= f; }
            m = logit;
        }
        const float p = __expf(logit - m);
        se += p;

        #pragma unroll
        for (int k = 0; k < 12; ++k) {
            const float z = fmaf(st.x, xv[k], -st.y);   // normalized value
            const float u = p * z;
            T1[k] += u;
            T2[k] = fmaf(u, z, T2[k]);
        }
    }

    if (lane == 0) lds_ms[wv] = m;
    __syncthreads();
    const float M = fmaxf(fmaxf(lds_ms[0], lds_ms[1]), fmaxf(lds_ms[2], lds_ms[3]));
    const float f = __expf(m - M);

    // epilogue: affine transform moments -> (a1, a2), scale by f, stage to LDS
    #pragma unroll
    for (int k = 0; k < 12; ++k) {
        const float cbS = cb[k] * se;
        const float a1  = fmaf(w[k], T1[k], cbS);
        const float a2  = fmaf(w[k]*w[k], T2[k],
                          fmaf(2.0f*w[k]*cb[k], T1[k], cb[k]*cbS));
        lds_acc[wv][(k/4)*256 + 4*lane + (k&3)]     = a1 * f;
        lds_acc[wv][D + (k/4)*256 + 4*lane + (k&3)] = a2 * f;
    }
    if (lane == 0) lds_se[wv] = se * f;
    __syncthreads();

    float* part = ws + WS_PART + (size_t)rb * PART_STRIDE;
    if (tid == 0) {
        part[0] = M;
        part[1] = lds_se[0] + lds_se[1] + lds_se[2] + lds_se[3];
    }
    #pragma unroll
    for (int k = 0; k < 6; ++k) {
        const int idx = tid + 256*k;     // 0..1535
        part[8 + idx] = lds_acc[0][idx] + lds_acc[1][idx] + lds_acc[2][idx] + lds_acc[3][idx];
    }
}

// ---------------- KD: combine partials -> out ----------------
// grid = 16 b * 6 col-tiles(128), block 128
__global__ __launch_bounds__(128) void kd_combine(const float* __restrict__ ws,
                                                  float* __restrict__ out) {
    __shared__ float lds_f[128];
    __shared__ float red[4];
    const int tid  = threadIdx.x;          // 0..127
    const int lane = tid & 63;
    const int wv   = tid >> 6;
    const int b    = blockIdx.x / 6;
    const int jt   = blockIdx.x % 6;
    const float* pb = ws + WS_PART + (size_t)b * BLOCKS_PER_B * PART_STRIDE;

    const float mc = pb[(size_t)tid * PART_STRIDE + 0];
    const float sc = pb[(size_t)tid * PART_STRIDE + 1];

    float M = mc;
    #pragma unroll
    for (int off = 32; off; off >>= 1) M = fmaxf(M, __shfl_xor(M, off));
    if (lane == 0) red[wv] = M;
    __syncthreads();
    M = fmaxf(red[0], red[1]);

    const float fc = __expf(mc - M);
    float fs = fc * sc;
    #pragma unroll
    for (int off = 32; off; off >>= 1) fs += __shfl_xor(fs, off);
    if (lane == 0) red[2 + wv] = fs;
    lds_f[tid] = fc;
    __syncthreads();
    const float S = red[2] + red[3];
    const float G = __uint_as_float(((const unsigned int*)ws)[WS_GMIN]) - EPS_POOL;

    const int d = jt * 128 + tid;
    float A1 = 0.0f, A2 = 0.0f;
    for (int c = 0; c < BLOCKS_PER_B; ++c) {
        const float* p = pb + (size_t)c * PART_STRIDE;
        const float w = lds_f[c];
        A1 += w * p[8 + d];
        A2 += w * p[8 + D + d];
    }
    const float e1 = A1 / S;
    const float e2 = A2 / S;
    const float v  = e2 - 2.0f * G * e1 + G * G;
    out[(size_t)b * D + d] = sqrtf(fmaxf(v, 0.0f));
}

// ---------------- launch ----------------
extern "C" void kernel_launch(void* const* d_in, const int* in_sizes, int n_in,
                              void* d_out, int out_size, void* d_ws, size_t ws_size,
                              hipStream_t stream) {
    const float* x   = (const float*)d_in[0];
    const float* lnw = (const float*)d_in[1];
    const float* lnb = (const float*)d_in[2];
    const float* wq  = (const float*)d_in[3];
    const float* wk  = (const float*)d_in[4];
    float* ws  = (float*)d_ws;   // needs ~13.9 MB
    float* out = (float*)d_out;

    hipLaunchKernelGGL(k0_init,   dim3(96),        dim3(256), 0, stream, ws);
    hipLaunchKernelGGL(ka_stats,  dim3(NBLK_PASS), dim3(256), 0, stream, x, lnw, lnb, ws);
    hipLaunchKernelGGL(kb1_qq,    dim3(192),       dim3(256), 0, stream, wq, ws);
    hipLaunchKernelGGL(kb2_r,     dim3(48),        dim3(256), 0, stream, wk, ws);
    hipLaunchKernelGGL(kc_fused,  dim3(NBLK_PASS), dim3(256), 0, stream, x, lnw, lnb, ws);
    hipLaunchKernelGGL(kd_combine,dim3(96),        dim3(128), 0, stream, ws, out);
}